// Round 4
// baseline (818.196 us; speedup 1.0000x reference)
//
#include <hip/hip_runtime.h>
#include <hip/hip_bf16.h>

// VQ argmin via bf16 MFMA + exact fp64 refine. Round 4: drop As LDS buffer
// (A-frags stream global->reg, dbuf), col-partition x2 -> 2 blocks/CU.
// out[0:N*D) = inputs; out[N*D : N*D+N) = argmin indices as f32.
// Scratch carved from d_out[0:N*D):
//   Xb   bf16[N][D]   @ float ofs 0          (32 MiB)
//   Cbb  bf16[K][D]   @ float ofs  8388608   ( 8 MiB)
//   cand int[N][128]  @ float ofs 10485760   (16 MiB)
// c2 f32[K] lives in d_ws (32 KiB).

constexpr int NTOK = 32768, DIM = 512, KCODES = 8192;
constexpr int BM = 128, BN = 128;
constexpr int NCTB = 32;           // col-tiles per block (half the codebook)
constexpr int TT  = NCTB * 16;     // 512 k-tiles per block (BK=32)
constexpr float MARGIN = 3.0f;

using bfrag = __attribute__((ext_vector_type(8))) short;   // 8 bf16 (4 VGPR)
using ffrag = __attribute__((ext_vector_type(4))) float;   // 4 f32 acc
using u16x8 = __attribute__((ext_vector_type(8))) unsigned short;

#define GLD_LDS16(g, l)                                                        \
  __builtin_amdgcn_global_load_lds(                                            \
      (const __attribute__((address_space(1))) void*)(g),                      \
      (__attribute__((address_space(3))) void*)(l), 16, 0, 0)
#define VMW(N) asm volatile("s_waitcnt vmcnt(" #N ")" ::: "memory")

__device__ __forceinline__ unsigned short f2bf(float x) {  // RNE
  unsigned u = __float_as_uint(x);
  return (unsigned short)((u + 0x7fffu + ((u >> 16) & 1u)) >> 16);
}

// ---- convert fp32 rows -> bf16, optional sum-of-squares (one wave per row) --
__global__ void vq_prep(const float* __restrict__ src, unsigned short* __restrict__ dst,
                        float* __restrict__ sq, int rows) {
  int w = (blockIdx.x * blockDim.x + threadIdx.x) >> 6;
  int lane = threadIdx.x & 63;
  if (w >= rows) return;
  const float4* r4 = (const float4*)(src + (size_t)w * DIM);
  float4 a = r4[lane * 2], b = r4[lane * 2 + 1];
  u16x8 o;
  o[0]=f2bf(a.x); o[1]=f2bf(a.y); o[2]=f2bf(a.z); o[3]=f2bf(a.w);
  o[4]=f2bf(b.x); o[5]=f2bf(b.y); o[6]=f2bf(b.z); o[7]=f2bf(b.w);
  *((u16x8*)(dst + (size_t)w * DIM) + lane) = o;
  if (sq != nullptr) {
    float s = a.x*a.x + a.y*a.y + a.z*a.z + a.w*a.w
            + b.x*b.x + b.y*b.y + b.z*b.z + b.w*b.w;
    #pragma unroll
    for (int off = 32; off; off >>= 1) s += __shfl_down(s, off, 64);
    if (lane == 0) sq[w] = s;
  }
}

// ---- fused bf16 MFMA distance + approx best-2 + candidate emission ---------
// Block: BM=128 rows x 4096 codes (half). 4 waves: wr=wid>>1 (row half),
// wc=wid&1 (col half of the 128-wide tile).
__launch_bounds__(256, 2)
__global__ void vq_main(const unsigned short* __restrict__ Xb,
                        const unsigned short* __restrict__ Cbb,
                        const float* __restrict__ c2g, int* __restrict__ cand) {
  __shared__ __align__(16) unsigned short Bs[3][BN][32];    // 24 KiB ring-3
  __shared__ __align__(16) float c2s[2][BN];                // 1 KiB ring-2
  __shared__ unsigned dstar[2][BM];                         // 1 KiB
  const int tid = threadIdx.x, lane = tid & 63;
  const int wid = tid >> 6, wr = wid >> 1, wc = wid & 1;
  const int rb = blockIdx.x & 255, h = blockIdx.x >> 8;
  const int row0 = rb * BM, ctBase = h * NCTB;
  const int l15 = lane & 15, l4 = lane >> 4;

  // per-thread A base: row wr*64 + rf*16 + l15, cols l4*8..
  const unsigned short* aBase =
      Xb + (size_t)(row0 + wr * 64 + l15) * DIM + l4 * 8;

  // ---------- prologue: stage B tiles 0..2, load A(0) ----------
  #pragma unroll
  for (int t0 = 0; t0 < 3; ++t0) {
    #pragma unroll
    for (int i2 = 0; i2 < 2; ++i2) {
      int u = i2 * 256 + tid, r = u >> 2, m = u & 3;
      GLD_LDS16(Cbb + (size_t)(ctBase * BN + r) * DIM + t0 * 32 +
                    ((m ^ ((r >> 1) & 3)) << 3),
                &Bs[t0][0][0] + u * 8);
    }
  }
  bfrag aF[2][4], bF[2][4];
  #pragma unroll
  for (int rf = 0; rf < 4; ++rf)
    aF[0][rf] = *(const bfrag*)(aBase + (size_t)rf * 16 * DIM);
  VMW(0);
  __builtin_amdgcn_s_barrier();
  #pragma unroll
  for (int cf = 0; cf < 4; ++cf) {
    int r = wc * 64 + cf * 16 + l15;
    bF[0][cf] = *(const bfrag*)&Bs[0][r][(l4 ^ ((r >> 1) & 3)) << 3];
  }

  unsigned b0k[4][4], b1k[4][4];
  #pragma unroll
  for (int rf = 0; rf < 4; ++rf)
    #pragma unroll
    for (int rg = 0; rg < 4; ++rg) { b0k[rf][rg] = 0xFFFFFFFFu; b1k[rf][rg] = 0xFFFFFFFFu; }
  ffrag acc[4][4];

  for (int ctl = 0; ctl < NCTB; ++ctl) {
    const int ct = ctBase + ctl;
    const bool last_ct = (ctl == NCTB - 1);
    #pragma unroll
    for (int kc = 0; kc < 16; ++kc) {
      const int t = ctl * 16 + kc;
      // own ds_reads (issued last iter) completed under MFMAs; drain + sync
      asm volatile("s_waitcnt lgkmcnt(0)" ::: "memory");
      __builtin_amdgcn_s_barrier();

      // issue A(t+1) global->reg (4 dwordx4)
      if (t + 1 < TT) {
        const int kcn = (kc + 1) & 15, pn = (kc + 1) & 1;
        #pragma unroll
        for (int rf = 0; rf < 4; ++rf)
          aF[pn][rf] = *(const bfrag*)(aBase + (size_t)rf * 16 * DIM + kcn * 32);
      }
      // issue S(t+3): stage B tile into slot (t+3)%3
      if (t + 3 < TT) {
        const int tt = t + 3, ctn = ctBase + (tt >> 4), kn = tt & 15, sl = tt % 3;
        #pragma unroll
        for (int i2 = 0; i2 < 2; ++i2) {
          int u = i2 * 256 + tid, r = u >> 2, m = u & 3;
          GLD_LDS16(Cbb + (size_t)(ctn * BN + r) * DIM + kn * 32 +
                        ((m ^ ((r >> 1) & 3)) << 3),
                    &Bs[sl][0][0] + u * 8);
        }
      }
      if (kc == 0 && lane < 32)   // c2 for this ct (read at kc==15)
        GLD_LDS16(c2g + ct * BN + lane * 4, &c2s[ctl & 1][0] + lane * 4);

      // counted vmcnt: ensure S(t+1) (for bF prefetch) and A(t) (for MFMA)
      // landed; keep S(t+2)/A(t+1)/S(t+3)(+c2) in flight.
      if (!last_ct || kc < 13) {
        if (kc == 0 || kc == 1) { VMW(9); } else { VMW(8); }
      } else {
        if (kc == 13) { VMW(6); } else if (kc == 14) { VMW(4); } else { VMW(0); }
      }

      // prefetch bF(t+1) from LDS (completes under this iter's MFMAs)
      if (t + 1 < TT) {
        const int pn = (kc + 1) & 1, sln = (t + 1) % 3;
        #pragma unroll
        for (int cf = 0; cf < 4; ++cf) {
          int r = wc * 64 + cf * 16 + l15;
          bF[pn][cf] = *(const bfrag*)&Bs[sln][r][(l4 ^ ((r >> 1) & 3)) << 3];
        }
      }

      // MFMA (zero-init accumulate at kc==0)
      #pragma unroll
      for (int rf = 0; rf < 4; ++rf) {
        const bfrag a = aF[kc & 1][rf];
        #pragma unroll
        for (int cf = 0; cf < 4; ++cf) {
          if (kc == 0) {
            ffrag z = {0.f, 0.f, 0.f, 0.f};
            acc[rf][cf] = __builtin_amdgcn_mfma_f32_16x16x32_bf16(a, bF[0][cf], z, 0, 0, 0);
          } else {
            acc[rf][cf] = __builtin_amdgcn_mfma_f32_16x16x32_bf16(a, bF[kc & 1][cf], acc[rf][cf], 0, 0, 0);
          }
        }
      }

      if (kc == 15) {   // per-col-tile epilogue: packed-key best-2 update
        float c2p[4];
        #pragma unroll
        for (int cf = 0; cf < 4; ++cf)
          c2p[cf] = c2s[ctl & 1][wc * 64 + cf * 16 + l15] + 2048.0f;  // key > 0
        #pragma unroll
        for (int rf = 0; rf < 4; ++rf)
          #pragma unroll
          for (int rg = 0; rg < 4; ++rg) {
            unsigned kk[4];
            #pragma unroll
            for (int cf = 0; cf < 4; ++cf) {
              float d = fmaf(-2.0f, acc[rf][cf][rg], c2p[cf]);
              kk[cf] = (__float_as_uint(d) & 0xFFFFFF00u) | (unsigned)((ct << 2) | cf);
            }
            unsigned kmin = min(min(kk[0], kk[1]), min(kk[2], kk[3]));
            unsigned mx = max(b0k[rf][rg], kmin);
            b0k[rf][rg] = min(b0k[rf][rg], kmin);
            b1k[rf][rg] = min(b1k[rf][rg], mx);
          }
      }
    }  // kc
  }    // ctl

  // per-row min across the 16 lanes sharing l4, cross-wave (wc) via LDS
  unsigned gmin[4][4];
  #pragma unroll
  for (int rf = 0; rf < 4; ++rf)
    #pragma unroll
    for (int rg = 0; rg < 4; ++rg) {
      unsigned g = b0k[rf][rg];
      #pragma unroll
      for (int m = 1; m < 16; m <<= 1)
        g = min(g, (unsigned)__shfl_xor((int)g, m, 64));
      gmin[rf][rg] = g;
      if (l15 == 0) dstar[wc][wr * 64 + rf * 16 + l4 * 4 + rg] = g;
    }
  __syncthreads();
  #pragma unroll
  for (int rf = 0; rf < 4; ++rf)
    #pragma unroll
    for (int rg = 0; rg < 4; ++rg) {
      int rl = wr * 64 + rf * 16 + l4 * 4 + rg;
      unsigned gg = min(gmin[rf][rg], dstar[wc ^ 1][rl]);
      float ds = __uint_as_float(gg & 0xFFFFFF00u);
      unsigned thr = __float_as_uint(ds + MARGIN);
      int base = (row0 + rl) * 128 + h * 64 + wc * 32 + l15 * 2;
      unsigned k0 = b0k[rf][rg], k1 = b1k[rf][rg];
      int c0 = (int)(((k0 >> 2) & 63u) * 128u) + wc * 64 + (int)(k0 & 3u) * 16 + l15;
      int c1 = (int)(((k1 >> 2) & 63u) * 128u) + wc * 64 + (int)(k1 & 3u) * 16 + l15;
      cand[base + 0] = (k0 <= thr) ? c0 : -1;
      cand[base + 1] = (k1 <= thr) ? c1 : -1;
    }
}

// ---- exact fp64 refine over candidate set (one wave per row, 128 slots) ----
__global__ void vq_refine(const float* __restrict__ X, const float* __restrict__ Cb,
                          const int* __restrict__ cand, float* __restrict__ idx_out) {
  int row = (blockIdx.x * blockDim.x + threadIdx.x) >> 6;
  int lane = threadIdx.x & 63;
  if (row >= NTOK) return;
  int cv0 = cand[row * 128 + lane];
  int cv1 = cand[row * 128 + 64 + lane];
  unsigned long long m0 = __ballot(cv0 >= 0);
  unsigned long long m1 = __ballot(cv1 >= 0);
  if (__popcll(m0) + __popcll(m1) == 1) {
    int idx;
    if (m0) idx = __shfl(cv0, __ffsll(m0) - 1, 64);
    else    idx = __shfl(cv1, __ffsll(m1) - 1, 64);
    if (lane == 0) idx_out[row] = (float)idx;
    return;
  }
  const float4* x4 = (const float4*)(X + (size_t)row * DIM);
  float4 xa = x4[lane * 2], xb = x4[lane * 2 + 1];
  double bestd = 1e300; int besti = 0x7FFFFFFF;
  #pragma unroll
  for (int half = 0; half < 2; ++half) {
    unsigned long long mm = half ? m1 : m0;
    int cv = half ? cv1 : cv0;
    while (mm) {
      int src = __ffsll(mm) - 1; mm &= mm - 1;
      int idx = __shfl(cv, src, 64);
      const float4* c4 = (const float4*)(Cb + (size_t)idx * DIM);
      float4 ca = c4[lane * 2], cb = c4[lane * 2 + 1];
      double dt = (double)xa.x*ca.x + (double)xa.y*ca.y + (double)xa.z*ca.z + (double)xa.w*ca.w
                + (double)xb.x*cb.x + (double)xb.y*cb.y + (double)xb.z*cb.z + (double)xb.w*cb.w;
      double cc = (double)ca.x*ca.x + (double)ca.y*ca.y + (double)ca.z*ca.z + (double)ca.w*ca.w
                + (double)cb.x*cb.x + (double)cb.y*cb.y + (double)cb.z*cb.z + (double)cb.w*cb.w;
      double s = cc - 2.0 * dt;             // x2 omitted: per-row constant
      #pragma unroll
      for (int off = 32; off; off >>= 1) s += __shfl_down(s, off, 64);
      if (lane == 0 && (s < bestd || (s == bestd && idx < besti))) { bestd = s; besti = idx; }
    }
  }
  if (lane == 0) idx_out[row] = (float)besti;
}

// ---- final: quantized = inputs (runs LAST; overwrites scratch) -------------
__global__ void vq_copy(const float* __restrict__ in, float* __restrict__ out, int n4) {
  int i = blockIdx.x * blockDim.x + threadIdx.x;
  int st = gridDim.x * blockDim.x;
  const float4* s = (const float4*)in;
  float4* d = (float4*)out;
  for (; i < n4; i += st) d[i] = s[i];
}

extern "C" void kernel_launch(void* const* d_in, const int* in_sizes, int n_in,
                              void* d_out, int out_size, void* d_ws, size_t ws_size,
                              hipStream_t stream) {
  const float* X  = (const float*)d_in[0];
  const float* Cb = (const float*)d_in[1];
  float* out = (float*)d_out;

  unsigned short* Xb   = (unsigned short*)out;                // [N][D] bf16
  unsigned short* Cbb  = (unsigned short*)(out + 8388608);    // [K][D] bf16
  int*            cand = (int*)(out + 10485760);              // [N][128]
  float*          c2   = (float*)d_ws;                        // [K]
  float*          idx_out = out + (size_t)NTOK * DIM;

  vq_prep<<<KCODES / 4, 256, 0, stream>>>(Cb, Cbb, c2, KCODES);
  vq_prep<<<NTOK / 4, 256, 0, stream>>>(X, Xb, nullptr, NTOK);
  vq_main<<<512, 256, 0, stream>>>(Xb, Cbb, c2, cand);
  vq_refine<<<NTOK / 4, 256, 0, stream>>>(X, Cb, cand, idx_out);
  vq_copy<<<2048, 256, 0, stream>>>(X, out, NTOK * DIM / 4);
}

// Round 5
// 324.423 us; speedup vs baseline: 2.5220x; 2.5220x over previous
//
#include <hip/hip_runtime.h>
#include <hip/hip_bf16.h>

// VQ argmin via bf16 MFMA + exact fp64 refine. Round 5: As LDS-resident again,
// 512-thread blocks (8 waves = 2/SIMD), two independent ct-streams per block,
// ring-4 B tiles, VMW(0)-before-barrier, 1 barrier per 2 tiles.
// Scratch carved from d_out[0:N*D):
//   Xb   bf16[N][D]   @ float ofs 0          (32 MiB)
//   Cbb  bf16[K][D]   @ float ofs  8388608   ( 8 MiB)
//   cand int[N][128]  @ float ofs 10485760   (16 MiB)
// c2 f32[K] lives in d_ws.

constexpr int NTOK = 32768, DIM = 512, KCODES = 8192;
constexpr float MARGIN = 3.0f;

using bfrag = __attribute__((ext_vector_type(8))) short;   // 8 bf16 (4 VGPR)
using ffrag = __attribute__((ext_vector_type(4))) float;   // 4 f32 acc
using u16x8 = __attribute__((ext_vector_type(8))) unsigned short;

#define GLD_LDS16(g, l)                                                        \
  __builtin_amdgcn_global_load_lds(                                            \
      (const __attribute__((address_space(1))) void*)(g),                      \
      (__attribute__((address_space(3))) void*)(l), 16, 0, 0)

__device__ __forceinline__ unsigned short f2bf(float x) {  // RNE
  unsigned u = __float_as_uint(x);
  return (unsigned short)((u + 0x7fffu + ((u >> 16) & 1u)) >> 16);
}

// ---- convert fp32 rows -> bf16, optional sum-of-squares (one wave per row) --
__global__ void vq_prep(const float* __restrict__ src, unsigned short* __restrict__ dst,
                        float* __restrict__ sq, int rows) {
  int w = (blockIdx.x * blockDim.x + threadIdx.x) >> 6;
  int lane = threadIdx.x & 63;
  if (w >= rows) return;
  const float4* r4 = (const float4*)(src + (size_t)w * DIM);
  float4 a = r4[lane * 2], b = r4[lane * 2 + 1];
  u16x8 o;
  o[0]=f2bf(a.x); o[1]=f2bf(a.y); o[2]=f2bf(a.z); o[3]=f2bf(a.w);
  o[4]=f2bf(b.x); o[5]=f2bf(b.y); o[6]=f2bf(b.z); o[7]=f2bf(b.w);
  *((u16x8*)(dst + (size_t)w * DIM) + lane) = o;
  if (sq != nullptr) {
    float s = a.x*a.x + a.y*a.y + a.z*a.z + a.w*a.w
            + b.x*b.x + b.y*b.y + b.z*b.z + b.w*b.w;
    #pragma unroll
    for (int off = 32; off; off >>= 1) s += __shfl_down(s, off, 64);
    if (lane == 0) sq[w] = s;
  }
}

// ---- fused bf16 MFMA distance + approx best-2 + candidate emission ---------
__launch_bounds__(512, 2)
__global__ void vq_main(const unsigned short* __restrict__ Xb,
                        const unsigned short* __restrict__ Cbb,
                        const float* __restrict__ c2g, int* __restrict__ cand) {
  __shared__ __align__(16) unsigned short As[128][512];    // 131072 B
  __shared__ __align__(16) unsigned short Bs[4][128][32];  // 32768 B (ring-4)
  const int tid = threadIdx.x, lane = tid & 63;
  const int wid = tid >> 6;
  const int s = wid >> 2, wr = (wid >> 1) & 1, wc = wid & 1;
  const int row0 = blockIdx.x * 128;
  const int l15 = lane & 15, l4 = lane >> 4;

  // ---------- prologue ----------
  #pragma unroll
  for (int it = 0; it < 16; ++it) {   // X tile -> As (pre-swizzled source)
    int u = it * 512 + tid, r = u >> 6, m = u & 63;
    GLD_LDS16(Xb + (size_t)(row0 + r) * DIM + ((m ^ (r & 7)) << 3),
              &As[0][0] + u * 8);
  }
  #pragma unroll
  for (int i = 0; i < 4; ++i) {       // tiles (ct=i&1, kc=i>>1) -> slot i
    const int ctT = i & 1, kcT = i >> 1;
    GLD_LDS16(Cbb + (size_t)(ctT * 128 + (tid >> 2)) * DIM + kcT * 32 +
                  (((tid & 3) ^ ((tid >> 3) & 3)) << 3),
              &Bs[i][0][0] + tid * 8);
  }
  asm volatile("s_waitcnt vmcnt(0)" ::: "memory");
  __builtin_amdgcn_s_barrier();

  bfrag aF[2][4], bF[2][4];
  #pragma unroll
  for (int rf = 0; rf < 4; ++rf) {    // phase-0 a-frags (kc=0)
    int r = wr * 64 + rf * 16 + l15;
    aF[0][rf] = *(const bfrag*)&As[r][(l4 ^ (r & 7)) << 3];
  }
  #pragma unroll
  for (int cf = 0; cf < 4; ++cf) {    // phase-0 b-frags (slot = s)
    int rB = wc * 64 + cf * 16 + l15;
    bF[0][cf] = *(const bfrag*)&Bs[s][rB][(l4 ^ ((rB >> 1) & 3)) << 3];
  }

  unsigned b0k[4][4], b1k[4][4];
  #pragma unroll
  for (int rf = 0; rf < 4; ++rf)
    #pragma unroll
    for (int rg = 0; rg < 4; ++rg) { b0k[rf][rg] = 0xFFFFFFFFu; b1k[rf][rg] = 0xFFFFFFFFu; }
  ffrag acc[4][4];
  float c2v[4];

  for (int pp = 0; pp < 32; ++pp) {        // ct-pair loop (cts 2pp, 2pp+1)
    #pragma unroll
    for (int q = 0; q < 16; ++q) {         // phase = one k-tile per stream
      const int p = pp * 16 + q;
      asm volatile("s_waitcnt lgkmcnt(0)" ::: "memory");
      asm volatile("s_waitcnt vmcnt(0)" ::: "memory");
      __builtin_amdgcn_s_barrier();

      // stage phase p+2 tiles (both streams; slot (p&1)*2+{0,1} = tiles p's slots)
      {
        const int tn = p + 2;
        const int ctn2 = (tn >> 4) << 1, kcn = tn & 15, slb = (tn & 1) * 2;
        const int rS = tid >> 2;
        const int mS = ((tid & 3) ^ ((tid >> 3) & 3)) << 3;
        GLD_LDS16(Cbb + (size_t)(ctn2 * 128 + rS) * DIM + kcn * 32 + mS,
                  &Bs[slb][0][0] + tid * 8);
        GLD_LDS16(Cbb + (size_t)((ctn2 + 1) * 128 + rS) * DIM + kcn * 32 + mS,
                  &Bs[slb + 1][0][0] + tid * 8);
      }
      if (q == 0) {  // c2 for this wave's ct; drained by later VMW(0)s
        const int ct = pp * 2 + s;
        #pragma unroll
        for (int cf = 0; cf < 4; ++cf)
          c2v[cf] = c2g[ct * 128 + wc * 64 + cf * 16 + l15];
      }

      // frag-read phase p+1 (this wave's stream; lands under MFMAs below)
      {
        const int qn = (q + 1) & 15, bufN = (q + 1) & 1;
        const int sl = ((q + 1) & 1) * 2 + s;
        #pragma unroll
        for (int rf = 0; rf < 4; ++rf) {
          int r = wr * 64 + rf * 16 + l15;
          aF[bufN][rf] = *(const bfrag*)&As[r][(((qn << 2) + l4) ^ (r & 7)) << 3];
        }
        #pragma unroll
        for (int cf = 0; cf < 4; ++cf) {
          int rB = wc * 64 + cf * 16 + l15;
          bF[bufN][cf] = *(const bfrag*)&Bs[sl][rB][(l4 ^ ((rB >> 1) & 3)) << 3];
        }
      }

      // MFMA current phase (regs read last phase; zero-init at kc==0)
      #pragma unroll
      for (int rf = 0; rf < 4; ++rf)
        #pragma unroll
        for (int cf = 0; cf < 4; ++cf) {
          if (q == 0) {
            ffrag z = {0.f, 0.f, 0.f, 0.f};
            acc[rf][cf] = __builtin_amdgcn_mfma_f32_16x16x32_bf16(aF[0][rf], bF[0][cf], z, 0, 0, 0);
          } else {
            acc[rf][cf] = __builtin_amdgcn_mfma_f32_16x16x32_bf16(aF[q & 1][rf], bF[q & 1][cf], acc[rf][cf], 0, 0, 0);
          }
        }

      if (q == 15) {   // per-ct epilogue: packed-key best-2 update
        const int ct = pp * 2 + s;
        #pragma unroll
        for (int rf = 0; rf < 4; ++rf)
          #pragma unroll
          for (int rg = 0; rg < 4; ++rg) {
            unsigned kk[4];
            #pragma unroll
            for (int cf = 0; cf < 4; ++cf) {
              float d = fmaf(-2.0f, acc[rf][cf][rg], c2v[cf] + 2048.0f);  // key>0
              kk[cf] = (__float_as_uint(d) & 0xFFFFFF00u) | (unsigned)((ct << 2) | cf);
            }
            unsigned kmin = min(min(kk[0], kk[1]), min(kk[2], kk[3]));
            unsigned mx = max(b0k[rf][rg], kmin);
            b0k[rf][rg] = min(b0k[rf][rg], kmin);
            b1k[rf][rg] = min(b1k[rf][rg], mx);
          }
      }
    }  // q
  }    // pp

  asm volatile("s_waitcnt lgkmcnt(0)" ::: "memory");
  __builtin_amdgcn_s_barrier();

  // per-row min across 16 l15-lanes; cross-(s,wc) via LDS (reuse Bs as dstar)
  unsigned* dstar = (unsigned*)&Bs[0][0][0];   // [4][128]
  unsigned gmin[4][4];
  #pragma unroll
  for (int rf = 0; rf < 4; ++rf)
    #pragma unroll
    for (int rg = 0; rg < 4; ++rg) {
      unsigned g = b0k[rf][rg];
      #pragma unroll
      for (int m = 1; m < 16; m <<= 1)
        g = min(g, (unsigned)__shfl_xor((int)g, m, 64));
      gmin[rf][rg] = g;
      if (l15 == 0) dstar[(s * 2 + wc) * 128 + wr * 64 + rf * 16 + l4 * 4 + rg] = g;
    }
  __syncthreads();
  #pragma unroll
  for (int rf = 0; rf < 4; ++rf)
    #pragma unroll
    for (int rg = 0; rg < 4; ++rg) {
      int rl = wr * 64 + rf * 16 + l4 * 4 + rg;
      unsigned gg = min(min(dstar[0 * 128 + rl], dstar[1 * 128 + rl]),
                        min(dstar[2 * 128 + rl], dstar[3 * 128 + rl]));
      float ds = __uint_as_float(gg & 0xFFFFFF00u);
      unsigned thr = __float_as_uint(ds + MARGIN);
      int base = (row0 + rl) * 128 + s * 64 + wc * 32 + l15 * 2;
      unsigned k0 = b0k[rf][rg], k1 = b1k[rf][rg];
      int c0 = (int)(((k0 >> 2) & 63u) * 128u) + wc * 64 + (int)(k0 & 3u) * 16 + l15;
      int c1 = (int)(((k1 >> 2) & 63u) * 128u) + wc * 64 + (int)(k1 & 3u) * 16 + l15;
      cand[base + 0] = (k0 <= thr) ? c0 : -1;
      cand[base + 1] = (k1 <= thr) ? c1 : -1;
    }
}

// ---- exact fp64 refine over candidate set (one wave per row, 128 slots) ----
__global__ void vq_refine(const float* __restrict__ X, const float* __restrict__ Cb,
                          const int* __restrict__ cand, float* __restrict__ idx_out) {
  int row = (blockIdx.x * blockDim.x + threadIdx.x) >> 6;
  int lane = threadIdx.x & 63;
  if (row >= NTOK) return;
  int cv0 = cand[row * 128 + lane];
  int cv1 = cand[row * 128 + 64 + lane];
  unsigned long long m0 = __ballot(cv0 >= 0);
  unsigned long long m1 = __ballot(cv1 >= 0);
  if (__popcll(m0) + __popcll(m1) == 1) {
    int idx;
    if (m0) idx = __shfl(cv0, __ffsll(m0) - 1, 64);
    else    idx = __shfl(cv1, __ffsll(m1) - 1, 64);
    if (lane == 0) idx_out[row] = (float)idx;
    return;
  }
  const float4* x4 = (const float4*)(X + (size_t)row * DIM);
  float4 xa = x4[lane * 2], xb = x4[lane * 2 + 1];
  double bestd = 1e300; int besti = 0x7FFFFFFF;
  #pragma unroll
  for (int half = 0; half < 2; ++half) {
    unsigned long long mm = half ? m1 : m0;
    int cv = half ? cv1 : cv0;
    while (mm) {
      int src = __ffsll(mm) - 1; mm &= mm - 1;
      int idx = __shfl(cv, src, 64);
      const float4* c4 = (const float4*)(Cb + (size_t)idx * DIM);
      float4 ca = c4[lane * 2], cb = c4[lane * 2 + 1];
      double dt = (double)xa.x*ca.x + (double)xa.y*ca.y + (double)xa.z*ca.z + (double)xa.w*ca.w
                + (double)xb.x*cb.x + (double)xb.y*cb.y + (double)xb.z*cb.z + (double)xb.w*cb.w;
      double cc = (double)ca.x*ca.x + (double)ca.y*ca.y + (double)ca.z*ca.z + (double)ca.w*ca.w
                + (double)cb.x*cb.x + (double)cb.y*cb.y + (double)cb.z*cb.z + (double)cb.w*cb.w;
      double sdist = cc - 2.0 * dt;           // x2 omitted: per-row constant
      #pragma unroll
      for (int off = 32; off; off >>= 1) sdist += __shfl_down(sdist, off, 64);
      if (lane == 0 && (sdist < bestd || (sdist == bestd && idx < besti))) { bestd = sdist; besti = idx; }
    }
  }
  if (lane == 0) idx_out[row] = (float)besti;
}

// ---- final: quantized = inputs (runs LAST; overwrites scratch) -------------
__global__ void vq_copy(const float* __restrict__ in, float* __restrict__ out, int n4) {
  int i = blockIdx.x * blockDim.x + threadIdx.x;
  int st = gridDim.x * blockDim.x;
  const float4* s = (const float4*)in;
  float4* d = (float4*)out;
  for (; i < n4; i += st) d[i] = s[i];
}

extern "C" void kernel_launch(void* const* d_in, const int* in_sizes, int n_in,
                              void* d_out, int out_size, void* d_ws, size_t ws_size,
                              hipStream_t stream) {
  const float* X  = (const float*)d_in[0];
  const float* Cb = (const float*)d_in[1];
  float* out = (float*)d_out;

  unsigned short* Xb   = (unsigned short*)out;                // [N][D] bf16
  unsigned short* Cbb  = (unsigned short*)(out + 8388608);    // [K][D] bf16
  int*            cand = (int*)(out + 10485760);              // [N][128]
  float*          c2   = (float*)d_ws;                        // [K]
  float*          idx_out = out + (size_t)NTOK * DIM;

  vq_prep<<<KCODES / 4, 256, 0, stream>>>(Cb, Cbb, c2, KCODES);
  vq_prep<<<NTOK / 4, 256, 0, stream>>>(X, Xb, nullptr, NTOK);
  vq_main<<<NTOK / 128, 512, 0, stream>>>(Xb, Cbb, c2, cand);
  vq_refine<<<NTOK / 4, 256, 0, stream>>>(X, Cb, cand, idx_out);
  vq_copy<<<2048, 256, 0, stream>>>(X, out, NTOK * DIM / 4);
}